// Round 12
// baseline (170.037 us; speedup 1.0000x reference)
//
#include <hip/hip_runtime.h>
#include <stdint.h>

typedef unsigned short u16;
typedef unsigned int   u32;
typedef short short8 __attribute__((ext_vector_type(8)));
typedef float f32x4  __attribute__((ext_vector_type(4)));

// ---------- helpers ----------
__device__ __forceinline__ u16 f2bf(float f){
  u32 u = __builtin_bit_cast(u32, f);
  u32 r = (u + 0x7FFFu + ((u >> 16) & 1u)) >> 16;   // RNE
  return (u16)r;
}
__device__ __forceinline__ u32 cvtpk(float a, float b){   // lo=bf16(a), hi=bf16(b), RNE
  u32 r; asm("v_cvt_pk_bf16_f32 %0, %1, %2" : "=v"(r) : "v"(a), "v"(b)); return r;
}
// async global->LDS, 16B per lane. LDS dest = wave-uniform base + lane*16.
__device__ __forceinline__ void gload16(const u16* g, u16* l){
  __builtin_amdgcn_global_load_lds((const __attribute__((address_space(1))) void*)g,
                                   (__attribute__((address_space(3))) void*)l, 16, 0, 0);
}
#define BARRIER()  do{ __builtin_amdgcn_s_barrier(); __builtin_amdgcn_sched_barrier(0); }while(0)

// ---------- x f32 -> bf16 ----------
__global__ __launch_bounds__(256) void k_cvt_bf16(const float* __restrict__ x,
                                                  u16* __restrict__ y, int n8){
  int i = blockIdx.x * 256 + threadIdx.x;
  if (i >= n8) return;
  const float4* p = (const float4*)x + (size_t)i * 2;
  float4 a = p[0], b = p[1];
  short8 o;
  o[0] = f2bf(a.x); o[1] = f2bf(a.y); o[2] = f2bf(a.z); o[3] = f2bf(a.w);
  o[4] = f2bf(b.x); o[5] = f2bf(b.y); o[6] = f2bf(b.z); o[7] = f2bf(b.w);
  *(short8*)(y + (size_t)i * 8) = o;
}

// ---------- weight transpose: in f32[R][C] -> out bf16[C][R] ----------
__global__ __launch_bounds__(256) void k_transpose_w(const float* __restrict__ in,
                                                     u16* __restrict__ out, int R, int C){
  __shared__ float tile[32][33];
  int nc = C >> 5;
  int cb = blockIdx.x % nc, rb = blockIdx.x / nc;
  int tx = threadIdx.x & 31, ty = threadIdx.x >> 5;
#pragma unroll
  for (int i = 0; i < 4; ++i){
    int r = rb * 32 + ty + i * 8;
    tile[ty + i * 8][tx] = in[(size_t)r * C + cb * 32 + tx];
  }
  __syncthreads();
#pragma unroll
  for (int i = 0; i < 4; ++i){
    int c = cb * 32 + ty + i * 8;
    out[(size_t)c * R + rb * 32 + tx] = f2bf(tile[tx][ty + i * 8]);
  }
}

// ---------- 4-wave counted-vmcnt GEMM: C[M][N] = A[M][K] * Bt[N][K]^T ----------
// 256 threads = 4 waves (2m x 2n), wave-tile (BM/2) x (NF*16). BK=32 (64-B rows,
// swizzle col^=((row&3)<<4): max 2-way LDS aliasing = free). 3 LDS buffers,
// 2-K-tile prefetch lead. T4 discipline: EVERY cross-wave LDS read is preceded by
// {counted vmcnt certifying the producing stage} + {s_barrier making it block-wide}.
// Two such points per K-tile (entry, mid); vmcnt never drains to 0 in steady state.
//   entry: [vmcnt(TL)+bar from prev iter] stage(kt+2) | rd aN (buf kt) | MFMA top (aP x bf)
//   mid:   vmcnt(TL) | bar | rd aP,bfN (buf kt+1) | MFMA bot (aN x bf) | bf=bfN
// Round-11 bug fixed here: the mid-point barrier was missing -> wave Y read B-slices
// staged by wave X before X's loads landed (vmcnt is wave-local).
template<int BM, int BN, int NF, bool QSCALE, typename CT>
__global__ __launch_bounds__(256) void k_gemm4w(const u16* __restrict__ A,
                                                const u16* __restrict__ Bt,
                                                CT* __restrict__ C,
                                                int N, int K){
  constexpr int MFR     = BM / 32;        // m-frags per wave
  constexpr int MHALF   = MFR / 2;
  constexpr int ALOADS  = BM / 64;        // per-thread A gloads per K-tile
  constexpr int BSLICES = BN / 16;        // 1KB B slices per K-tile
  constexpr int TL      = ALOADS + 2;     // per-thread loads per K-tile (uniform)
  constexpr int SZ      = (BM + BN) * 64; // bytes per buffer
  __shared__ char lds[3 * SZ + 1024];     // +1KB dump line for dummy B loads

  int tid = threadIdx.x, lane = tid & 63, wid = tid >> 6;
  int l16 = lane & 15, g4 = lane >> 4;
  int wm = wid >> 1, wn = wid & 1;
  int bid = blockIdx.x;
  int cpx = (int)gridDim.x >> 3;
  int wg = (bid & 7) * cpx + (bid >> 3);
  int nb = N / BN;
  int bm = wg / nb, bn = wg % nb;

  const u16* baseA = A  + (size_t)(bm * BM) * K;
  const u16* baseB = Bt + (size_t)(bn * BN) * K;

  // A staging: q covers BM*64 bytes linearly; global col inverse-swizzled
  int aLds[ALOADS], aG[ALOADS];
#pragma unroll
  for (int i = 0; i < ALOADS; ++i){
    int q = (wid * ALOADS + i) * 1024 + lane * 16;
    int row = q >> 6, c = q & 63;
    int cs = c ^ ((row & 3) << 4);
    aLds[i] = q; aG[i] = row * K + (cs >> 1);
  }
  // B staging: 2 slices per wave; slice >= BSLICES -> dump line
  int bLds[2], bG[2]; bool bOk[2];
#pragma unroll
  for (int j = 0; j < 2; ++j){
    int slice = wid + j * 4;
    bOk[j] = (slice < BSLICES);
    int s = bOk[j] ? slice : 0;
    int q = s * 1024 + lane * 16;
    int row = q >> 6, c = q & 63;
    int cs = c ^ ((row & 3) << 4);
    bLds[j] = bOk[j] ? (BM * 64 + q) : (3 * SZ + lane * 16);
    bG[j] = row * K + (cs >> 1);
  }
  auto stage = [&](int t){
    char* dst = lds + (t % 3) * SZ;
#pragma unroll
    for (int i = 0; i < ALOADS; ++i) gload16(baseA + aG[i] + t * 32, (u16*)(dst + aLds[i]));
#pragma unroll
    for (int j = 0; j < 2; ++j){
      char* d = bOk[j] ? (dst + bLds[j]) : (lds + bLds[j]);
      gload16(baseB + bG[j] + t * 32, (u16*)d);
    }
  };
  auto rdA = [&](int buf, int m){
    int row = wm * (BM / 2) + m * 16 + l16;
    return *(const short8*)(lds + buf * SZ + row * 64 + ((g4 * 16) ^ ((row & 3) << 4)));
  };
  auto rdB = [&](int buf, int nf){
    int row = wn * (NF * 16) + nf * 16 + l16;
    return *(const short8*)(lds + buf * SZ + BM * 64 + row * 64 + ((g4 * 16) ^ ((row & 3) << 4)));
  };

  f32x4 zero4 = {0.f, 0.f, 0.f, 0.f};
  f32x4 acc[MFR][NF];
#pragma unroll
  for (int i = 0; i < MFR; ++i)
#pragma unroll
    for (int j = 0; j < NF; ++j) acc[i][j] = zero4;

  short8 aP[MHALF], aN[MHALF], bf[NF], bfN[NF];

  int NK = K >> 5;
  stage(0); stage(1);
  if constexpr (TL == 6) asm volatile("s_waitcnt vmcnt(6)" ::: "memory");
  else                   asm volatile("s_waitcnt vmcnt(4)" ::: "memory");
  BARRIER();                 // all waves' stage(0) complete
#pragma unroll
  for (int m = 0; m < MHALF; ++m) aP[m] = rdA(0, m);
#pragma unroll
  for (int f = 0; f < NF; ++f)    bf[f] = rdB(0, f);

  for (int kt = 0; kt < NK; ++kt){
    int bcur = kt % 3;
    BARRIER();                                  // entry: buf(kt-1) reads all retired (block-wide)
    if (kt + 2 < NK) stage(kt + 2);             // overwrites buf((kt-1)%3)
#pragma unroll
    for (int m = 0; m < MHALF; ++m) aN[m] = rdA(bcur, MHALF + m);
    __builtin_amdgcn_s_setprio(1);
#pragma unroll
    for (int m = 0; m < MHALF; ++m)
#pragma unroll
      for (int f = 0; f < NF; ++f)
        acc[m][f] = __builtin_amdgcn_mfma_f32_16x16x32_bf16(aP[m], bf[f], acc[m][f], 0, 0, 0);
    __builtin_amdgcn_s_setprio(0);
    if (kt + 1 < NK){
      // mid-point: certify stage(kt+1) in THIS wave (counted), then barrier ->
      // stage(kt+1) complete in ALL waves; only then read buf(kt+1).
      if (kt + 2 < NK){
        if constexpr (TL == 6) asm volatile("s_waitcnt vmcnt(6)" ::: "memory");
        else                   asm volatile("s_waitcnt vmcnt(4)" ::: "memory");
      } else {
        asm volatile("s_waitcnt vmcnt(0)" ::: "memory");
      }
      BARRIER();                                // <-- the round-11 missing barrier
      int bnext = (kt + 1) % 3;
#pragma unroll
      for (int m = 0; m < MHALF; ++m) aP[m] = rdA(bnext, m);
#pragma unroll
      for (int f = 0; f < NF; ++f)    bfN[f] = rdB(bnext, f);
    }
    __builtin_amdgcn_s_setprio(1);
#pragma unroll
    for (int m = 0; m < MHALF; ++m)
#pragma unroll
      for (int f = 0; f < NF; ++f)
        acc[MHALF + m][f] = __builtin_amdgcn_mfma_f32_16x16x32_bf16(aN[m], bf[f], acc[MHALF + m][f], 0, 0, 0);
    __builtin_amdgcn_s_setprio(0);
    if (kt + 1 < NK){
#pragma unroll
      for (int f = 0; f < NF; ++f) bf[f] = bfN[f];
    }
  }

#pragma unroll
  for (int mf = 0; mf < MFR; ++mf)
#pragma unroll
    for (int nf = 0; nf < NF; ++nf)
#pragma unroll
      for (int r = 0; r < 4; ++r){
        int row = bm * BM + wm * (BM / 2) + mf * 16 + g4 * 4 + r;
        int col = bn * BN + wn * (NF * 16) + nf * 16 + l16;
        float vv = acc[mf][nf][r];
        if constexpr (QSCALE) { if (col < 2048) vv *= 0.18033688011112042f; }  // log2(e)/8
        if constexpr (sizeof(CT) == 2) C[(size_t)row * N + col] = (CT)f2bf(vv);
        else                           C[(size_t)row * N + col] = (CT)vv;
      }
}

// ---------- V transpose: c1 V-part [bv*256+s][2560+n*64+h] -> vt[(bv*8+n)*64+h][256 s] ----------
__global__ __launch_bounds__(256) void k_vt(const u16* __restrict__ c1, u16* __restrict__ vt){
  __shared__ u16 tile[64][72];
  int bid = blockIdx.x;
  int st = bid & 3, n = (bid >> 2) & 7, bv = bid >> 5;   // bv = b*8+v (0..15)
  int t = threadIdx.x;
  int sr = t >> 2, sc = t & 3;
  const u16* src = c1 + (size_t)(bv * 256 + st * 64 + sr) * 3072 + 2560 + n * 64 + sc * 16;
  short8 a = *(const short8*)src;
  short8 b = *(const short8*)(src + 8);
  *(short8*)&tile[sr][sc * 16]     = a;
  *(short8*)&tile[sr][sc * 16 + 8] = b;
  __syncthreads();
  int h = t >> 2, c2 = t & 3;
  short8 o0, o1;
#pragma unroll
  for (int j = 0; j < 8; ++j) o0[j] = (short)tile[c2 * 16 + j][h];
#pragma unroll
  for (int j = 0; j < 8; ++j) o1[j] = (short)tile[c2 * 16 + 8 + j][h];
  u16* dst = vt + (size_t)((bv * 8 + n) * 64 + h) * 256 + st * 64 + c2 * 16;
  *(short8*)dst       = o0;
  *(short8*)(dst + 8) = o1;
}

// ---------- fused GQA neighbor attention ----------
// block = (b, v, n, qtile64); grid 512; 4 waves = 4 GQA groups sharing K/V LDS.
// QBLK=64 geometry + prescaled-Q (exp2 domain), defer-max (THR=8), cvt_pk packing.
__global__ __launch_bounds__(256, 2) void k_attn(const u16* __restrict__ c1,
                                                 const u16* __restrict__ vt,
                                                 u16* __restrict__ att){
  __shared__ u16 Klds[64][72];
  __shared__ u16 Vlds[64][72];
  __shared__ u16 Plds[4][16][72];
  int bid = blockIdx.x;
  int qt = bid & 3, n = (bid >> 2) & 7, v = (bid >> 5) & 7, b = bid >> 8;
  int tid = threadIdx.x;
  int g = tid >> 6, lane = tid & 63, l16 = lane & 15, g4 = lane >> 4;
  int bv = b * 8 + v;
  int rowQ = bv * 256 + qt * 64;
  int qcol = n * 256 + g * 64;

  short8 qf[4][2];
#pragma unroll
  for (int qi = 0; qi < 4; ++qi)
#pragma unroll
    for (int kk = 0; kk < 2; ++kk)
      qf[qi][kk] = *(const short8*)(c1 + (size_t)(rowQ + qi * 16 + l16) * 3072
                                     + qcol + kk * 32 + g4 * 8);

  f32x4 zero4 = {0.f, 0.f, 0.f, 0.f};
  f32x4 O[4][4];
#pragma unroll
  for (int i = 0; i < 4; ++i)
#pragma unroll
    for (int j = 0; j < 4; ++j) O[i][j] = zero4;
  float m2[4]   = {-3.0e38f, -3.0e38f, -3.0e38f, -3.0e38f};
  float lsum[4] = {0.f, 0.f, 0.f, 0.f};

  int sr = tid >> 2, sc = tid & 3;
  short8 k0, k1, v0, v1;
  {
    int vn = (v + 7) & 7;
    const u16* ks = c1 + (size_t)((b * 8 + vn) * 256 + sr) * 3072 + 2048 + n * 64 + sc * 16;
    k0 = *(const short8*)ks; k1 = *(const short8*)(ks + 8);
    const u16* vs = vt + (size_t)(((b * 8 + vn) * 8 + n) * 64 + sr) * 256 + sc * 16;
    v0 = *(const short8*)vs; v1 = *(const short8*)(vs + 8);
  }

  for (int ti = 0; ti < 8; ++ti){
    __syncthreads();
    *(short8*)&Klds[sr][sc * 16]     = k0;
    *(short8*)&Klds[sr][sc * 16 + 8] = k1;
    *(short8*)&Vlds[sr][sc * 16]     = v0;
    *(short8*)&Vlds[sr][sc * 16 + 8] = v1;
    __syncthreads();
    if (ti < 7){
      int tn = ti + 1;
      int vn = (tn < 4) ? ((v + 7) & 7) : ((v + 1) & 7);
      int tb = (tn & 3) * 64;
      const u16* ks = c1 + (size_t)((b * 8 + vn) * 256 + tb + sr) * 3072 + 2048 + n * 64 + sc * 16;
      k0 = *(const short8*)ks; k1 = *(const short8*)(ks + 8);
      const u16* vs = vt + (size_t)(((b * 8 + vn) * 8 + n) * 64 + sr) * 256 + tb + sc * 16;
      v0 = *(const short8*)vs; v1 = *(const short8*)(vs + 8);
    }
    short8 kf[4][2], vf[2][4];
#pragma unroll
    for (int kt = 0; kt < 4; ++kt)
#pragma unroll
      for (int ks = 0; ks < 2; ++ks)
        kf[kt][ks] = *(const short8*)&Klds[kt * 16 + l16][ks * 32 + g4 * 8];
#pragma unroll
    for (int ks = 0; ks < 2; ++ks)
#pragma unroll
      for (int hi = 0; hi < 4; ++hi)
        vf[ks][hi] = *(const short8*)&Vlds[hi * 16 + l16][ks * 32 + g4 * 8];

#pragma unroll
    for (int qi = 0; qi < 4; ++qi){
      f32x4 sa[4];
#pragma unroll
      for (int kt = 0; kt < 4; ++kt){
        sa[kt] = zero4;
#pragma unroll
        for (int ks = 0; ks < 2; ++ks)
          sa[kt] = __builtin_amdgcn_mfma_f32_16x16x32_bf16(kf[kt][ks], qf[qi][ks], sa[kt], 0, 0, 0);
      }
      float pmax = sa[0][0];
#pragma unroll
      for (int kt = 0; kt < 4; ++kt)
#pragma unroll
        for (int r = 0; r < 4; ++r) pmax = fmaxf(pmax, sa[kt][r]);
      pmax = fmaxf(pmax, __shfl_xor(pmax, 16));
      pmax = fmaxf(pmax, __shfl_xor(pmax, 32));
      if (__any(pmax > m2[qi] + 8.f)){
        float mnew  = fmaxf(m2[qi], pmax);
        float alpha = exp2f(m2[qi] - mnew);
        m2[qi] = mnew;
        lsum[qi] *= alpha;
        float ab[4];
#pragma unroll
        for (int r = 0; r < 4; ++r) ab[r] = __shfl(alpha, g4 * 4 + r);
#pragma unroll
        for (int hi = 0; hi < 4; ++hi)
#pragma unroll
          for (int r = 0; r < 4; ++r) O[qi][hi][r] *= ab[r];
      }
      float m = m2[qi];
      float psum = 0.f;
      u32 w[4][2];
#pragma unroll
      for (int kt = 0; kt < 4; ++kt){
        float p0 = exp2f(sa[kt][0] - m);
        float p1 = exp2f(sa[kt][1] - m);
        float p2 = exp2f(sa[kt][2] - m);
        float p3 = exp2f(sa[kt][3] - m);
        psum += (p0 + p1) + (p2 + p3);
        w[kt][0] = cvtpk(p0, p1);
        w[kt][1] = cvtpk(p2, p3);
      }
      psum += __shfl_xor(psum, 16);
      psum += __shfl_xor(psum, 32);
      lsum[qi] += psum;
      u32* prow = (u32*)&Plds[g][l16][0];
#pragma unroll
      for (int kt = 0; kt < 4; ++kt){
        prow[kt * 8 + g4 * 2]     = w[kt][0];
        prow[kt * 8 + g4 * 2 + 1] = w[kt][1];
      }
      short8 pa[2];
#pragma unroll
      for (int ks = 0; ks < 2; ++ks)
        pa[ks] = *(const short8*)&Plds[g][l16][ks * 32 + g4 * 8];
#pragma unroll
      for (int hi = 0; hi < 4; ++hi)
#pragma unroll
        for (int ks = 0; ks < 2; ++ks)
          O[qi][hi] = __builtin_amdgcn_mfma_f32_16x16x32_bf16(pa[ks], vf[ks][hi], O[qi][hi], 0, 0, 0);
    }
  }
#pragma unroll
  for (int qi = 0; qi < 4; ++qi){
    float lb[4];
#pragma unroll
    for (int r = 0; r < 4; ++r) lb[r] = 1.0f / __shfl(lsum[qi], g4 * 4 + r);
#pragma unroll
    for (int hi = 0; hi < 4; ++hi)
#pragma unroll
      for (int r = 0; r < 4; ++r){
        int row = rowQ + qi * 16 + g4 * 4 + r;
        int col = qcol + hi * 16 + l16;
        att[(size_t)row * 2048 + col] = f2bf(O[qi][hi][r] * lb[r]);
      }
  }
}

extern "C" void kernel_launch(void* const* d_in, const int* in_sizes, int n_in,
                              void* d_out, int out_size, void* d_ws, size_t ws_size,
                              hipStream_t stream){
  const float* x   = (const float*)d_in[0];
  const float* wq  = (const float*)d_in[1];
  const float* wkv = (const float*)d_in[2];
  const float* wo  = (const float*)d_in[3];
  float* out = (float*)d_out;
  char* ws = (char*)d_ws;

  // workspace layout (67,108,864 B total)
  u16* x_bf  = (u16*)(ws);               // [4096][2048] bf16, 16.78 MB (aliased by att)
  u16* wqkvt = (u16*)(ws + 16777216);    // [3072][2048] bf16, 12.58 MB
  u16* wot   = (u16*)(ws + 29360128);    // [2048][2048] bf16,  8.39 MB
  u16* c1    = (u16*)(ws + 37748736);    // [4096][3072] bf16, 25.17 MB (Q|K|V)
  u16* vt    = (u16*)(ws + 62914560);    // [16*8][64][256] bf16, 4.19 MB
  u16* att   = x_bf;                     // alias: x_bf dead after GEMM1

  k_cvt_bf16<<<4096, 256, 0, stream>>>(x, x_bf, 1048576);
  k_transpose_w<<<4096, 256, 0, stream>>>(wq,  wqkvt,               2048, 2048);
  k_transpose_w<<<2048, 256, 0, stream>>>(wkv, wqkvt + 2048 * 2048, 2048, 1024);
  k_transpose_w<<<4096, 256, 0, stream>>>(wo,  wot,                 2048, 2048);
  // QKV projection (Q cols pre-scaled): BM=256 BN=96, grid 16x32=512 = 2/CU
  k_gemm4w<256, 96, 3, true,  u16  ><<<512, 256, 0, stream>>>(x_bf, wqkvt, c1, 3072, 2048);
  k_vt<<<512, 256, 0, stream>>>(c1, vt);
  k_attn<<<512, 256, 0, stream>>>(c1, vt, att);
  // output projection: BM=128 BN=128, grid 32x16=512 = 2/CU
  k_gemm4w<128, 128, 4, false, float><<<512, 256, 0, stream>>>(att, wot, out, 2048, 2048);
}

// Round 13
// 155.459 us; speedup vs baseline: 1.0938x; 1.0938x over previous
//
#include <hip/hip_runtime.h>
#include <stdint.h>

typedef unsigned short u16;
typedef unsigned int   u32;
typedef short short8 __attribute__((ext_vector_type(8)));
typedef float f32x4  __attribute__((ext_vector_type(4)));

// ---------- helpers ----------
__device__ __forceinline__ u16 f2bf(float f){
  u32 u = __builtin_bit_cast(u32, f);
  u32 r = (u + 0x7FFFu + ((u >> 16) & 1u)) >> 16;   // RNE
  return (u16)r;
}
__device__ __forceinline__ u32 cvtpk(float a, float b){   // lo=bf16(a), hi=bf16(b), RNE
  u32 r; asm("v_cvt_pk_bf16_f32 %0, %1, %2" : "=v"(r) : "v"(a), "v"(b)); return r;
}
// async global->LDS, 16B per lane. LDS dest = wave-uniform base + lane*16.
__device__ __forceinline__ void gload16(const u16* g, u16* l){
  __builtin_amdgcn_global_load_lds((const __attribute__((address_space(1))) void*)g,
                                   (__attribute__((address_space(3))) void*)l, 16, 0, 0);
}
#define BARRIER()  do{ __builtin_amdgcn_s_barrier(); __builtin_amdgcn_sched_barrier(0); }while(0)

// ---------- x f32 -> bf16 ----------
__global__ __launch_bounds__(256) void k_cvt_bf16(const float* __restrict__ x,
                                                  u16* __restrict__ y, int n8){
  int i = blockIdx.x * 256 + threadIdx.x;
  if (i >= n8) return;
  const float4* p = (const float4*)x + (size_t)i * 2;
  float4 a = p[0], b = p[1];
  short8 o;
  o[0] = f2bf(a.x); o[1] = f2bf(a.y); o[2] = f2bf(a.z); o[3] = f2bf(a.w);
  o[4] = f2bf(b.x); o[5] = f2bf(b.y); o[6] = f2bf(b.z); o[7] = f2bf(b.w);
  *(short8*)(y + (size_t)i * 8) = o;
}

// ---------- weight transpose: in f32[R][C] -> out bf16[C][R] ----------
__global__ __launch_bounds__(256) void k_transpose_w(const float* __restrict__ in,
                                                     u16* __restrict__ out, int R, int C){
  __shared__ float tile[32][33];
  int nc = C >> 5;
  int cb = blockIdx.x % nc, rb = blockIdx.x / nc;
  int tx = threadIdx.x & 31, ty = threadIdx.x >> 5;
#pragma unroll
  for (int i = 0; i < 4; ++i){
    int r = rb * 32 + ty + i * 8;
    tile[ty + i * 8][tx] = in[(size_t)r * C + cb * 32 + tx];
  }
  __syncthreads();
#pragma unroll
  for (int i = 0; i < 4; ++i){
    int c = cb * 32 + ty + i * 8;
    out[(size_t)c * R + rb * 32 + tx] = f2bf(tile[tx][ty + i * 8]);
  }
}

// ---------- m201-style 8-wave 4-phase GEMM: C[M][N] = A[M][K] * Bt[N][K]^T ----------
// 512 threads = 8 waves (2m x 4n). BK=64, 128-B LDS rows, swizzle col^=((row&7)<<4)
// (verified 0 bank conflicts, r10). 2 LDS buffers. Per K-tile, 4 phases (mh x ks):
//   {ds-reads for THIS phase | 1-2 stage issues (tile kt+1) | BAR | setprio+MFMA | [vmcnt] | BAR}
// Counted vmcnt (T4) twice per K-tile, never 0 in steady state:
//   end-P3: vmcnt(F3) -> P0-needed loads (B*, A-half0 blocks) certified; newest F3 fly.
//   end-P0: vmcnt(2)  -> A-half1 blocks certified; kt+2's B0,B1 fly.
// Stage order per tile: B0..B_{BL-1}, then A blocks in half-consumption order.
// A-frag row maps chosen so mh0 rows = first-staged A blocks:
//   MFR=8: row=wm*128+mf*16  (mh0 -> blocks 0,2; order A0,A2,A1,A3; F3=2)
//   MFR=4: row=(mf>>1)*64+wm*32+(mf&1)*16 (mh0 -> block 0; order A0,A1; F3=1)
template<int BM, int BN, int MFR, int NF, bool QSCALE, typename CT>
__global__ __launch_bounds__(512) void k_gemm8m(const u16* __restrict__ A,
                                                const u16* __restrict__ Bt,
                                                CT* __restrict__ C,
                                                int N, int K){
  constexpr int MH  = MFR / 2;
  constexpr int AL  = BM / 64, BL = BN / 64, L = AL + BL;
  constexpr int SZA = BM * 128;
  constexpr int SZ  = (BM + BN) * 128;
  constexpr int F3  = (MFR == 8) ? 2 : 1;
  __shared__ char lds[2 * SZ];

  int tid = threadIdx.x, lane = tid & 63, wid = tid >> 6;
  int l16 = lane & 15, g4 = lane >> 4;
  int wm = wid >> 2, wn = wid & 3;
  int bid = blockIdx.x;
  int wg = (bid & 7) * 32 + (bid >> 3);    // 256 blocks, 32 contiguous wg / XCD
  int nb = N / BN;
  int bm = wg / nb, bn = wg % nb;

  const u16* baseA = A  + (size_t)(bm * BM) * K;
  const u16* baseB = Bt + (size_t)(bn * BN) * K;

  // staging: linear LDS dest (block i -> bytes [i*8192,(i+1)*8192)); global source
  // col inverse-swizzled (involution)
  int aG[AL], bG[BL];
#pragma unroll
  for (int i = 0; i < AL; ++i){
    int q = i * 8192 + tid * 16;
    int row = q >> 7, c = q & 127;
    int cs = c ^ ((row & 7) << 4);
    aG[i] = row * K + (cs >> 1);
  }
#pragma unroll
  for (int j = 0; j < BL; ++j){
    int q = j * 8192 + tid * 16;
    int row = q >> 7, c = q & 127;
    int cs = c ^ ((row & 7) << 4);
    bG[j] = row * K + (cs >> 1);
  }
  auto stageL = [&](int t, int l){
    char* dst = lds + (t & 1) * SZ;
    if (l < BL){
      gload16(baseB + bG[l] + t * 64, (u16*)(dst + SZA + l * 8192 + tid * 16));
    } else {
      int i;
      if constexpr (MFR == 8){ constexpr int ord[4] = {0, 2, 1, 3}; i = ord[l - BL]; }
      else                   { i = l - BL; }
      gload16(baseA + aG[i] + t * 64, (u16*)(dst + i * 8192 + tid * 16));
    }
  };
  auto aRowBase = [&](int mf){
    if constexpr (MFR == 8) return wm * 128 + mf * 16;
    else                    return (mf >> 1) * 64 + wm * 32 + (mf & 1) * 16;
  };
  auto rdA = [&](const char* buf, int mf, int ks){
    int row = aRowBase(mf) + l16;
    return *(const short8*)(buf + row * 128 + ((ks * 64 + g4 * 16) ^ ((row & 7) << 4)));
  };
  auto rdB = [&](const char* buf, int nf, int ks){
    int row = wn * (NF * 16) + nf * 16 + l16;
    return *(const short8*)(buf + SZA + row * 128 + ((ks * 64 + g4 * 16) ^ ((row & 7) << 4)));
  };

  f32x4 zero4 = {0.f, 0.f, 0.f, 0.f};
  f32x4 acc[MFR][NF];
#pragma unroll
  for (int i = 0; i < MFR; ++i)
#pragma unroll
    for (int j = 0; j < NF; ++j) acc[i][j] = zero4;

  int NK = K >> 6;
  // prologue: full stage of tile 0
#pragma unroll
  for (int l = 0; l < L; ++l) stageL(0, l);
  asm volatile("s_waitcnt vmcnt(0)" ::: "memory");
  BARRIER();

  short8 av[MH], bv[NF];
  for (int kt = 0; kt < NK; ++kt){
    const char* buf = lds + (kt & 1) * SZ;
    bool st = (kt + 1 < NK);
    // ---- P0 (mh0, ks0): reads incl. B(ks0) | stage B0,B1 | MFMA | vmcnt | bar
#pragma unroll
    for (int nf = 0; nf < NF; ++nf) bv[nf] = rdB(buf, nf, 0);
#pragma unroll
    for (int m = 0; m < MH; ++m)    av[m] = rdA(buf, m, 0);
    if (st){ stageL(kt + 1, 0); stageL(kt + 1, 1); }
    BARRIER();
    __builtin_amdgcn_s_setprio(1);
#pragma unroll
    for (int m = 0; m < MH; ++m)
#pragma unroll
      for (int nf = 0; nf < NF; ++nf)
        acc[m][nf] = __builtin_amdgcn_mfma_f32_16x16x32_bf16(av[m], bv[nf], acc[m][nf], 0, 0, 0);
    __builtin_amdgcn_s_setprio(0);
    if (st) asm volatile("s_waitcnt vmcnt(2)" ::: "memory");   // A-half1 blocks certified
    else    asm volatile("s_waitcnt vmcnt(0)" ::: "memory");
    BARRIER();
    // ---- P1 (mh1, ks0): | stage idx 2,3 | MFMA | bar
#pragma unroll
    for (int m = 0; m < MH; ++m) av[m] = rdA(buf, MH + m, 0);
    if (st){ stageL(kt + 1, 2); stageL(kt + 1, 3); }
    BARRIER();
    __builtin_amdgcn_s_setprio(1);
#pragma unroll
    for (int m = 0; m < MH; ++m)
#pragma unroll
      for (int nf = 0; nf < NF; ++nf)
        acc[MH + m][nf] = __builtin_amdgcn_mfma_f32_16x16x32_bf16(av[m], bv[nf], acc[MH + m][nf], 0, 0, 0);
    __builtin_amdgcn_s_setprio(0);
    BARRIER();
    // ---- P2 (mh0, ks1): reads incl. B(ks1) | stage idx 4..L-2 | MFMA | bar
#pragma unroll
    for (int nf = 0; nf < NF; ++nf) bv[nf] = rdB(buf, nf, 1);
#pragma unroll
    for (int m = 0; m < MH; ++m)    av[m] = rdA(buf, m, 1);
    if (st){
#pragma unroll
      for (int l = 4; l < L - 1; ++l) stageL(kt + 1, l);
    }
    BARRIER();
    __builtin_amdgcn_s_setprio(1);
#pragma unroll
    for (int m = 0; m < MH; ++m)
#pragma unroll
      for (int nf = 0; nf < NF; ++nf)
        acc[m][nf] = __builtin_amdgcn_mfma_f32_16x16x32_bf16(av[m], bv[nf], acc[m][nf], 0, 0, 0);
    __builtin_amdgcn_s_setprio(0);
    BARRIER();
    // ---- P3 (mh1, ks1): | stage idx L-1 | MFMA | counted vmcnt | bar
#pragma unroll
    for (int m = 0; m < MH; ++m) av[m] = rdA(buf, MH + m, 1);
    if (st) stageL(kt + 1, L - 1);
    BARRIER();
    __builtin_amdgcn_s_setprio(1);
#pragma unroll
    for (int m = 0; m < MH; ++m)
#pragma unroll
      for (int nf = 0; nf < NF; ++nf)
        acc[MH + m][nf] = __builtin_amdgcn_mfma_f32_16x16x32_bf16(av[m], bv[nf], acc[MH + m][nf], 0, 0, 0);
    __builtin_amdgcn_s_setprio(0);
    if (st){
      if constexpr (F3 == 2) asm volatile("s_waitcnt vmcnt(2)" ::: "memory");
      else                   asm volatile("s_waitcnt vmcnt(1)" ::: "memory");
    }
    BARRIER();
  }

#pragma unroll
  for (int mf = 0; mf < MFR; ++mf)
#pragma unroll
    for (int nf = 0; nf < NF; ++nf)
#pragma unroll
      for (int r = 0; r < 4; ++r){
        int row = bm * BM + aRowBase(mf) + g4 * 4 + r;
        int col = bn * BN + wn * (NF * 16) + nf * 16 + l16;
        float vv = acc[mf][nf][r];
        if constexpr (QSCALE) { if (col < 2048) vv *= 0.18033688011112042f; }  // log2(e)/8
        if constexpr (sizeof(CT) == 2) C[(size_t)row * N + col] = (CT)f2bf(vv);
        else                           C[(size_t)row * N + col] = (CT)vv;
      }
}

// ---------- V transpose: c1 V-part [bv*256+s][2560+n*64+h] -> vt[(bv*8+n)*64+h][256 s] ----------
__global__ __launch_bounds__(256) void k_vt(const u16* __restrict__ c1, u16* __restrict__ vt){
  __shared__ u16 tile[64][72];
  int bid = blockIdx.x;
  int st = bid & 3, n = (bid >> 2) & 7, bv = bid >> 5;   // bv = b*8+v (0..15)
  int t = threadIdx.x;
  int sr = t >> 2, sc = t & 3;
  const u16* src = c1 + (size_t)(bv * 256 + st * 64 + sr) * 3072 + 2560 + n * 64 + sc * 16;
  short8 a = *(const short8*)src;
  short8 b = *(const short8*)(src + 8);
  *(short8*)&tile[sr][sc * 16]     = a;
  *(short8*)&tile[sr][sc * 16 + 8] = b;
  __syncthreads();
  int h = t >> 2, c2 = t & 3;
  short8 o0, o1;
#pragma unroll
  for (int j = 0; j < 8; ++j) o0[j] = (short)tile[c2 * 16 + j][h];
#pragma unroll
  for (int j = 0; j < 8; ++j) o1[j] = (short)tile[c2 * 16 + 8 + j][h];
  u16* dst = vt + (size_t)((bv * 8 + n) * 64 + h) * 256 + st * 64 + c2 * 16;
  *(short8*)dst       = o0;
  *(short8*)(dst + 8) = o1;
}

// ---------- fused GQA neighbor attention ----------
// block = (b, v, n, qtile64); grid 512; 4 waves = 4 GQA groups sharing K/V LDS.
// QBLK=64 geometry + prescaled-Q (exp2 domain), defer-max (THR=8), cvt_pk packing.
__global__ __launch_bounds__(256, 2) void k_attn(const u16* __restrict__ c1,
                                                 const u16* __restrict__ vt,
                                                 u16* __restrict__ att){
  __shared__ u16 Klds[64][72];
  __shared__ u16 Vlds[64][72];
  __shared__ u16 Plds[4][16][72];
  int bid = blockIdx.x;
  int qt = bid & 3, n = (bid >> 2) & 7, v = (bid >> 5) & 7, b = bid >> 8;
  int tid = threadIdx.x;
  int g = tid >> 6, lane = tid & 63, l16 = lane & 15, g4 = lane >> 4;
  int bv = b * 8 + v;
  int rowQ = bv * 256 + qt * 64;
  int qcol = n * 256 + g * 64;

  short8 qf[4][2];
#pragma unroll
  for (int qi = 0; qi < 4; ++qi)
#pragma unroll
    for (int kk = 0; kk < 2; ++kk)
      qf[qi][kk] = *(const short8*)(c1 + (size_t)(rowQ + qi * 16 + l16) * 3072
                                     + qcol + kk * 32 + g4 * 8);

  f32x4 zero4 = {0.f, 0.f, 0.f, 0.f};
  f32x4 O[4][4];
#pragma unroll
  for (int i = 0; i < 4; ++i)
#pragma unroll
    for (int j = 0; j < 4; ++j) O[i][j] = zero4;
  float m2[4]   = {-3.0e38f, -3.0e38f, -3.0e38f, -3.0e38f};
  float lsum[4] = {0.f, 0.f, 0.f, 0.f};

  int sr = tid >> 2, sc = tid & 3;
  short8 k0, k1, v0, v1;
  {
    int vn = (v + 7) & 7;
    const u16* ks = c1 + (size_t)((b * 8 + vn) * 256 + sr) * 3072 + 2048 + n * 64 + sc * 16;
    k0 = *(const short8*)ks; k1 = *(const short8*)(ks + 8);
    const u16* vs = vt + (size_t)(((b * 8 + vn) * 8 + n) * 64 + sr) * 256 + sc * 16;
    v0 = *(const short8*)vs; v1 = *(const short8*)(vs + 8);
  }

  for (int ti = 0; ti < 8; ++ti){
    __syncthreads();
    *(short8*)&Klds[sr][sc * 16]     = k0;
    *(short8*)&Klds[sr][sc * 16 + 8] = k1;
    *(short8*)&Vlds[sr][sc * 16]     = v0;
    *(short8*)&Vlds[sr][sc * 16 + 8] = v1;
    __syncthreads();
    if (ti < 7){
      int tn = ti + 1;
      int vn = (tn < 4) ? ((v + 7) & 7) : ((v + 1) & 7);
      int tb = (tn & 3) * 64;
      const u16* ks = c1 + (size_t)((b * 8 + vn) * 256 + tb + sr) * 3072 + 2048 + n * 64 + sc * 16;
      k0 = *(const short8*)ks; k1 = *(const short8*)(ks + 8);
      const u16* vs = vt + (size_t)(((b * 8 + vn) * 8 + n) * 64 + sr) * 256 + tb + sc * 16;
      v0 = *(const short8*)vs; v1 = *(const short8*)(vs + 8);
    }
    short8 kf[4][2], vf[2][4];
#pragma unroll
    for (int kt = 0; kt < 4; ++kt)
#pragma unroll
      for (int ks = 0; ks < 2; ++ks)
        kf[kt][ks] = *(const short8*)&Klds[kt * 16 + l16][ks * 32 + g4 * 8];
#pragma unroll
    for (int ks = 0; ks < 2; ++ks)
#pragma unroll
      for (int hi = 0; hi < 4; ++hi)
        vf[ks][hi] = *(const short8*)&Vlds[hi * 16 + l16][ks * 32 + g4 * 8];

#pragma unroll
    for (int qi = 0; qi < 4; ++qi){
      f32x4 sa[4];
#pragma unroll
      for (int kt = 0; kt < 4; ++kt){
        sa[kt] = zero4;
#pragma unroll
        for (int ks = 0; ks < 2; ++ks)
          sa[kt] = __builtin_amdgcn_mfma_f32_16x16x32_bf16(kf[kt][ks], qf[qi][ks], sa[kt], 0, 0, 0);
      }
      float pmax = sa[0][0];
#pragma unroll
      for (int kt = 0; kt < 4; ++kt)
#pragma unroll
        for (int r = 0; r < 4; ++r) pmax = fmaxf(pmax, sa[kt][r]);
      pmax = fmaxf(pmax, __shfl_xor(pmax, 16));
      pmax = fmaxf(pmax, __shfl_xor(pmax, 32));
      if (__any(pmax > m2[qi] + 8.f)){
        float mnew  = fmaxf(m2[qi], pmax);
        float alpha = exp2f(m2[qi] - mnew);
        m2[qi] = mnew;
        lsum[qi] *= alpha;
        float ab[4];
#pragma unroll
        for (int r = 0; r < 4; ++r) ab[r] = __shfl(alpha, g4 * 4 + r);
#pragma unroll
        for (int hi = 0; hi < 4; ++hi)
#pragma unroll
          for (int r = 0; r < 4; ++r) O[qi][hi][r] *= ab[r];
      }
      float m = m2[qi];
      float psum = 0.f;
      u32 w[4][2];
#pragma unroll
      for (int kt = 0; kt < 4; ++kt){
        float p0 = exp2f(sa[kt][0] - m);
        float p1 = exp2f(sa[kt][1] - m);
        float p2 = exp2f(sa[kt][2] - m);
        float p3 = exp2f(sa[kt][3] - m);
        psum += (p0 + p1) + (p2 + p3);
        w[kt][0] = cvtpk(p0, p1);
        w[kt][1] = cvtpk(p2, p3);
      }
      psum += __shfl_xor(psum, 16);
      psum += __shfl_xor(psum, 32);
      lsum[qi] += psum;
      u32* prow = (u32*)&Plds[g][l16][0];
#pragma unroll
      for (int kt = 0; kt < 4; ++kt){
        prow[kt * 8 + g4 * 2]     = w[kt][0];
        prow[kt * 8 + g4 * 2 + 1] = w[kt][1];
      }
      short8 pa[2];
#pragma unroll
      for (int ks = 0; ks < 2; ++ks)
        pa[ks] = *(const short8*)&Plds[g][l16][ks * 32 + g4 * 8];
#pragma unroll
      for (int hi = 0; hi < 4; ++hi)
#pragma unroll
        for (int ks = 0; ks < 2; ++ks)
          O[qi][hi] = __builtin_amdgcn_mfma_f32_16x16x32_bf16(pa[ks], vf[ks][hi], O[qi][hi], 0, 0, 0);
    }
  }
#pragma unroll
  for (int qi = 0; qi < 4; ++qi){
    float lb[4];
#pragma unroll
    for (int r = 0; r < 4; ++r) lb[r] = 1.0f / __shfl(lsum[qi], g4 * 4 + r);
#pragma unroll
    for (int hi = 0; hi < 4; ++hi)
#pragma unroll
      for (int r = 0; r < 4; ++r){
        int row = rowQ + qi * 16 + g4 * 4 + r;
        int col = qcol + hi * 16 + l16;
        att[(size_t)row * 2048 + col] = f2bf(O[qi][hi][r] * lb[r]);
      }
  }
}

extern "C" void kernel_launch(void* const* d_in, const int* in_sizes, int n_in,
                              void* d_out, int out_size, void* d_ws, size_t ws_size,
                              hipStream_t stream){
  const float* x   = (const float*)d_in[0];
  const float* wq  = (const float*)d_in[1];
  const float* wkv = (const float*)d_in[2];
  const float* wo  = (const float*)d_in[3];
  float* out = (float*)d_out;
  char* ws = (char*)d_ws;

  // workspace layout (67,108,864 B total)
  u16* x_bf  = (u16*)(ws);               // [4096][2048] bf16, 16.78 MB (aliased by att)
  u16* wqkvt = (u16*)(ws + 16777216);    // [3072][2048] bf16, 12.58 MB
  u16* wot   = (u16*)(ws + 29360128);    // [2048][2048] bf16,  8.39 MB
  u16* c1    = (u16*)(ws + 37748736);    // [4096][3072] bf16, 25.17 MB (Q|K|V)
  u16* vt    = (u16*)(ws + 62914560);    // [16*8][64][256] bf16, 4.19 MB
  u16* att   = x_bf;                     // alias: x_bf dead after GEMM1

  k_cvt_bf16<<<4096, 256, 0, stream>>>(x, x_bf, 1048576);
  k_transpose_w<<<4096, 256, 0, stream>>>(wq,  wqkvt,               2048, 2048);
  k_transpose_w<<<2048, 256, 0, stream>>>(wkv, wqkvt + 2048 * 2048, 2048, 1024);
  k_transpose_w<<<4096, 256, 0, stream>>>(wo,  wot,                 2048, 2048);
  // QKV projection (Q cols pre-scaled): BM=256 BN=192, grid 16x16=256, full fill
  k_gemm8m<256, 192, 8, 3, true,  u16  ><<<256, 512, 0, stream>>>(x_bf, wqkvt, c1, 3072, 2048);
  k_vt<<<512, 256, 0, stream>>>(c1, vt);
  k_attn<<<512, 256, 0, stream>>>(c1, vt, att);
  // output projection: BM=128 BN=256 (remapped A-frag rows), grid 32x8=256, full fill
  k_gemm8m<128, 256, 4, 4, false, float><<<256, 512, 0, stream>>>(att, wot, out, 2048, 2048);
}

// Round 14
// 150.290 us; speedup vs baseline: 1.1314x; 1.0344x over previous
//
#include <hip/hip_runtime.h>
#include <stdint.h>

typedef unsigned short u16;
typedef unsigned int   u32;
typedef short short8 __attribute__((ext_vector_type(8)));
typedef float f32x4  __attribute__((ext_vector_type(4)));

// ---------- helpers ----------
__device__ __forceinline__ u16 f2bf(float f){
  u32 u = __builtin_bit_cast(u32, f);
  u32 r = (u + 0x7FFFu + ((u >> 16) & 1u)) >> 16;   // RNE
  return (u16)r;
}
__device__ __forceinline__ u32 cvtpk(float a, float b){   // lo=bf16(a), hi=bf16(b), RNE
  u32 r; asm("v_cvt_pk_bf16_f32 %0, %1, %2" : "=v"(r) : "v"(a), "v"(b)); return r;
}
// async global->LDS, 16B per lane. LDS dest = wave-uniform base + lane*16.
__device__ __forceinline__ void gload16(const u16* g, u16* l){
  __builtin_amdgcn_global_load_lds((const __attribute__((address_space(1))) void*)g,
                                   (__attribute__((address_space(3))) void*)l, 16, 0, 0);
}
#define BARRIER()  do{ __builtin_amdgcn_s_barrier(); __builtin_amdgcn_sched_barrier(0); }while(0)

// ---------- fused preprocessing: x f32->bf16 + 3 weight transposes ----------
__device__ __forceinline__ void dev_transpose(const float* __restrict__ in,
                                              u16* __restrict__ out, int R, int C,
                                              int bid, int tx, int ty, float (*tile)[33]){
  int nc = C >> 5;
  int cb = bid % nc, rb = bid / nc;
#pragma unroll
  for (int i = 0; i < 4; ++i){
    int r = rb * 32 + ty + i * 8;
    tile[ty + i * 8][tx] = in[(size_t)r * C + cb * 32 + tx];
  }
  __syncthreads();
#pragma unroll
  for (int i = 0; i < 4; ++i){
    int c = cb * 32 + ty + i * 8;
    out[(size_t)c * R + rb * 32 + tx] = f2bf(tile[tx][ty + i * 8]);
  }
}

__global__ __launch_bounds__(256) void k_prep(const float* __restrict__ x,
                                              const float* __restrict__ wq,
                                              const float* __restrict__ wkv,
                                              const float* __restrict__ wo,
                                              u16* __restrict__ x_bf,
                                              u16* __restrict__ wqkvt,
                                              u16* __restrict__ wot){
  __shared__ float tile[32][33];
  int bid = blockIdx.x;
  if (bid < 4096){
    int i = bid * 256 + threadIdx.x;
    const float4* p = (const float4*)x + (size_t)i * 2;
    float4 a = p[0], b = p[1];
    short8 o;
    o[0] = f2bf(a.x); o[1] = f2bf(a.y); o[2] = f2bf(a.z); o[3] = f2bf(a.w);
    o[4] = f2bf(b.x); o[5] = f2bf(b.y); o[6] = f2bf(b.z); o[7] = f2bf(b.w);
    *(short8*)(x_bf + (size_t)i * 8) = o;
    return;
  }
  int tx = threadIdx.x & 31, ty = threadIdx.x >> 5;
  if (bid < 8192)       dev_transpose(wq,  wqkvt,               2048, 2048, bid - 4096,  tx, ty, tile);
  else if (bid < 10240) dev_transpose(wkv, wqkvt + 2048 * 2048, 2048, 1024, bid - 8192,  tx, ty, tile);
  else                  dev_transpose(wo,  wot,                 2048, 2048, bid - 10240, tx, ty, tile);
}

// ---------- pipelined GEMM (round-10 champion): C[M][N] = A[M][K] * Bt[N][K]^T ----------
// 512 threads = 8 waves (2m x 4n). BK=64, 2 LDS buffers, XOR-swizzled rows.
// Sized for 2 blocks/CU (grid 512, LDS <= 80KB): cross-block overlap hides
// barrier/phase latency. One-phase-ahead: every MFMA cluster consumes frags read
// the PREVIOUS phase. Measured: 52.8 us each, 0 bank conflicts (round 10).
template<int BM, int BN, int MH, int NFRAG, int ALOADS, int BLOADS, bool QSCALE, typename CT>
__global__ __launch_bounds__(512) void k_gemm8p(const u16* __restrict__ A,
                                                const u16* __restrict__ Bt,
                                                CT* __restrict__ C,
                                                int N, int K){
  constexpr int SZA = BM * 128;
  constexpr int SZB = BN * 128;
  constexpr int SZ  = SZA + SZB;
  constexpr int WTM = BM / 2;
  constexpr int WTN = BN / 4;
  __shared__ char lds[2 * SZ];

  int tid = threadIdx.x, lane = tid & 63, wid = tid >> 6;
  int l16 = lane & 15, g4 = lane >> 4;
  int wm = wid >> 2, wn = wid & 3;
  int bid = blockIdx.x;
  int cpx = (int)gridDim.x >> 3;
  int wg = (bid & 7) * cpx + (bid >> 3);
  int nb = N / BN;
  int bm = wg / nb, bn = wg % nb;

  const u16* baseA = A  + (size_t)(bm * BM) * K;
  const u16* baseB = Bt + (size_t)(bn * BN) * K;

  int aLds[ALOADS], aG[ALOADS];
#pragma unroll
  for (int i = 0; i < ALOADS; ++i){
    int q = (wid * ALOADS + i) * 1024 + lane * 16;
    int row = q >> 7, c = q & 127;
    int cs = c ^ ((row & 7) << 4);
    aLds[i] = q; aG[i] = row * K + (cs >> 1);
  }
  int bLds[BLOADS], bG[BLOADS];
#pragma unroll
  for (int j = 0; j < BLOADS; ++j){
    int q = (wid * BLOADS + j) * 1024 + lane * 16;
    int row = q >> 7, c = q & 127;
    int cs = c ^ ((row & 7) << 4);
    bLds[j] = q; bG[j] = row * K + (cs >> 1);
  }
  auto stageA = [&](int t){
    char* dst = lds + (t & 1) * SZ;
#pragma unroll
    for (int i = 0; i < ALOADS; ++i) gload16(baseA + aG[i] + t * 64, (u16*)(dst + aLds[i]));
  };
  auto stageB = [&](int t){
    char* dst = lds + (t & 1) * SZ + SZA;
#pragma unroll
    for (int j = 0; j < BLOADS; ++j) gload16(baseB + bG[j] + t * 64, (u16*)(dst + bLds[j]));
  };
  auto rdA = [&](const char* Ab, int m, int ks){
    int row = wm * WTM + m * 16 + l16;
    return *(const short8*)(Ab + row * 128 + ((ks * 64 + g4 * 16) ^ ((row & 7) << 4)));
  };
  auto rdB = [&](const char* Bb, int nf, int ks){
    int row = wn * WTN + nf * 16 + l16;
    return *(const short8*)(Bb + row * 128 + ((ks * 64 + g4 * 16) ^ ((row & 7) << 4)));
  };

  f32x4 zero4 = {0.f, 0.f, 0.f, 0.f};
  f32x4 acc[2 * MH][NFRAG];
#pragma unroll
  for (int i = 0; i < 2 * MH; ++i)
#pragma unroll
    for (int j = 0; j < NFRAG; ++j) acc[i][j] = zero4;

  int NK = K >> 6;
  stageA(0); stageB(0);
  asm volatile("s_waitcnt vmcnt(0)" ::: "memory");
  BARRIER();
  short8 a0[MH], a1[MH], a2[MH], a3[MH], bf0[NFRAG], bf1[NFRAG];
#pragma unroll
  for (int nf = 0; nf < NFRAG; ++nf) bf0[nf] = rdB(lds + SZA, nf, 0);
#pragma unroll
  for (int m = 0; m < MH; ++m)       a0[m]  = rdA(lds, m, 0);

  for (int kt = 0; kt < NK; ++kt){
    const char* Ab = lds + (kt & 1) * SZ;
    const char* Bb = Ab + SZA;
    bool st = (kt + 1 < NK);
    // phase a: rd a1 | stageA(kt+1) | bar | C0 = a0 x bf0
#pragma unroll
    for (int m = 0; m < MH; ++m) a1[m] = rdA(Ab, MH + m, 0);
    if (st) stageA(kt + 1);
    BARRIER();
    __builtin_amdgcn_s_setprio(1);
#pragma unroll
    for (int m = 0; m < MH; ++m)
#pragma unroll
      for (int nf = 0; nf < NFRAG; ++nf)
        acc[m][nf] = __builtin_amdgcn_mfma_f32_16x16x32_bf16(a0[m], bf0[nf], acc[m][nf], 0, 0, 0);
    __builtin_amdgcn_s_setprio(0);
    // phase b: rd bf1,a2 | stageB(kt+1) | bar | C1 = a1 x bf0
#pragma unroll
    for (int nf = 0; nf < NFRAG; ++nf) bf1[nf] = rdB(Bb, nf, 1);
#pragma unroll
    for (int m = 0; m < MH; ++m)       a2[m]  = rdA(Ab, m, 1);
    if (st) stageB(kt + 1);
    BARRIER();
    __builtin_amdgcn_s_setprio(1);
#pragma unroll
    for (int m = 0; m < MH; ++m)
#pragma unroll
      for (int nf = 0; nf < NFRAG; ++nf)
        acc[MH + m][nf] = __builtin_amdgcn_mfma_f32_16x16x32_bf16(a1[m], bf0[nf], acc[MH + m][nf], 0, 0, 0);
    __builtin_amdgcn_s_setprio(0);
    // phase c: rd a3 | bar | C2 = a2 x bf1
#pragma unroll
    for (int m = 0; m < MH; ++m) a3[m] = rdA(Ab, MH + m, 1);
    BARRIER();
    __builtin_amdgcn_s_setprio(1);
#pragma unroll
    for (int m = 0; m < MH; ++m)
#pragma unroll
      for (int nf = 0; nf < NFRAG; ++nf)
        acc[m][nf] = __builtin_amdgcn_mfma_f32_16x16x32_bf16(a2[m], bf1[nf], acc[m][nf], 0, 0, 0);
    __builtin_amdgcn_s_setprio(0);
    // phase d: vmcnt | bar | rd next a0,bf0 | C3 = a3 x bf1 | bar
    if (st) asm volatile("s_waitcnt vmcnt(0)" ::: "memory");
    BARRIER();
    if (st){
      const char* Ab2 = lds + ((kt + 1) & 1) * SZ;
      const char* Bb2 = Ab2 + SZA;
#pragma unroll
      for (int nf = 0; nf < NFRAG; ++nf) bf0[nf] = rdB(Bb2, nf, 0);
#pragma unroll
      for (int m = 0; m < MH; ++m)       a0[m]  = rdA(Ab2, m, 0);
    }
    __builtin_amdgcn_s_setprio(1);
#pragma unroll
    for (int m = 0; m < MH; ++m)
#pragma unroll
      for (int nf = 0; nf < NFRAG; ++nf)
        acc[MH + m][nf] = __builtin_amdgcn_mfma_f32_16x16x32_bf16(a3[m], bf1[nf], acc[MH + m][nf], 0, 0, 0);
    __builtin_amdgcn_s_setprio(0);
    BARRIER();
  }

#pragma unroll
  for (int mf = 0; mf < 2 * MH; ++mf)
#pragma unroll
    for (int nf = 0; nf < NFRAG; ++nf)
#pragma unroll
      for (int r = 0; r < 4; ++r){
        int row = bm * BM + wm * WTM + mf * 16 + g4 * 4 + r;
        int col = bn * BN + wn * WTN + nf * 16 + l16;
        float vv = acc[mf][nf][r];
        if constexpr (QSCALE) { if (col < 2048) vv *= 0.18033688011112042f; }  // log2(e)/8
        if constexpr (sizeof(CT) == 2) C[(size_t)row * N + col] = (CT)f2bf(vv);
        else                           C[(size_t)row * N + col] = (CT)vv;
      }
}

// ---------- V transpose: c1 V-part [bv*256+s][2560+n*64+h] -> vt[(bv*8+n)*64+h][256 s] ----------
__global__ __launch_bounds__(256) void k_vt(const u16* __restrict__ c1, u16* __restrict__ vt){
  __shared__ u16 tile[64][72];
  int bid = blockIdx.x;
  int st = bid & 3, n = (bid >> 2) & 7, bv = bid >> 5;   // bv = b*8+v (0..15)
  int t = threadIdx.x;
  int sr = t >> 2, sc = t & 3;
  const u16* src = c1 + (size_t)(bv * 256 + st * 64 + sr) * 3072 + 2560 + n * 64 + sc * 16;
  short8 a = *(const short8*)src;
  short8 b = *(const short8*)(src + 8);
  *(short8*)&tile[sr][sc * 16]     = a;
  *(short8*)&tile[sr][sc * 16 + 8] = b;
  __syncthreads();
  int h = t >> 2, c2 = t & 3;
  short8 o0, o1;
#pragma unroll
  for (int j = 0; j < 8; ++j) o0[j] = (short)tile[c2 * 16 + j][h];
#pragma unroll
  for (int j = 0; j < 8; ++j) o1[j] = (short)tile[c2 * 16 + 8 + j][h];
  u16* dst = vt + (size_t)((bv * 8 + n) * 64 + h) * 256 + st * 64 + c2 * 16;
  *(short8*)dst       = o0;
  *(short8*)(dst + 8) = o1;
}

// ---------- fused GQA neighbor attention ----------
// block = (b, v, n, qtile64); grid 512 (2 blocks/CU); 4 waves = 4 GQA groups.
// K/V staged via gload16 into linear [64][128B] LDS with (row&7)<<4 XOR swizzle
// (pre-swizzled per-lane global source; read applies same XOR — rule 21).
// Double-buffered: tile t+1's 4 gload16 issue at top of tile t; the single
// end-of-tile __syncthreads (implicit vmcnt drain) certifies them — T4-correct.
// Prescaled-Q (exp2 domain), defer-max (THR=8), cvt_pk packing.
__global__ __launch_bounds__(256, 2) void k_attn(const u16* __restrict__ c1,
                                                 const u16* __restrict__ vt,
                                                 u16* __restrict__ att){
  __shared__ char KV[2][16384];      // per buf: K [64][128B] then V [64][128B]
  __shared__ u16 Plds[4][16][72];
  int bid = blockIdx.x;
  int qt = bid & 3, n = (bid >> 2) & 7, v = (bid >> 5) & 7, b = bid >> 8;
  int tid = threadIdx.x;
  int g = tid >> 6, lane = tid & 63, l16 = lane & 15, g4 = lane >> 4;
  int bv = b * 8 + v;
  int rowQ = bv * 256 + qt * 64;
  int qcol = n * 256 + g * 64;

  // staging maps: thread covers q = i*4096 + tid*16 (i=0,1); source col inverse-swizzled
  int srow[2], scol[2], qo[2];
#pragma unroll
  for (int i = 0; i < 2; ++i){
    int q = i * 4096 + tid * 16;
    int row = q >> 7, c = q & 127;
    int cs = c ^ ((row & 7) << 4);
    srow[i] = row; scol[i] = cs >> 1; qo[i] = q;
  }
  auto stage = [&](int t, int buf){
    int vn = (t < 4) ? ((v + 7) & 7) : ((v + 1) & 7);
    int tb = (t & 3) * 64;
    const u16* kb = c1 + (size_t)((b * 8 + vn) * 256 + tb) * 3072 + 2048 + n * 64;
    const u16* vb = vt + (size_t)(((b * 8 + vn) * 8 + n) * 64) * 256 + tb;
    char* d = KV[buf];
#pragma unroll
    for (int i = 0; i < 2; ++i) gload16(kb + (size_t)srow[i] * 3072 + scol[i], (u16*)(d + qo[i]));
#pragma unroll
    for (int i = 0; i < 2; ++i) gload16(vb + (size_t)srow[i] * 256 + scol[i], (u16*)(d + 8192 + qo[i]));
  };
  auto rdK = [&](int buf, int kt, int ks){
    int row = kt * 16 + l16;
    return *(const short8*)(KV[buf] + row * 128 + ((ks * 64 + g4 * 16) ^ ((row & 7) << 4)));
  };
  auto rdV = [&](int buf, int hi, int ks){
    int row = hi * 16 + l16;
    return *(const short8*)(KV[buf] + 8192 + row * 128 + ((ks * 64 + g4 * 16) ^ ((row & 7) << 4)));
  };

  // hoist Q fragments (B-operand: col=qrow=l16, k=hd)
  short8 qf[4][2];
#pragma unroll
  for (int qi = 0; qi < 4; ++qi)
#pragma unroll
    for (int kk = 0; kk < 2; ++kk)
      qf[qi][kk] = *(const short8*)(c1 + (size_t)(rowQ + qi * 16 + l16) * 3072
                                     + qcol + kk * 32 + g4 * 8);

  f32x4 zero4 = {0.f, 0.f, 0.f, 0.f};
  f32x4 O[4][4];
#pragma unroll
  for (int i = 0; i < 4; ++i)
#pragma unroll
    for (int j = 0; j < 4; ++j) O[i][j] = zero4;
  float m2[4]   = {-3.0e38f, -3.0e38f, -3.0e38f, -3.0e38f};
  float lsum[4] = {0.f, 0.f, 0.f, 0.f};

  stage(0, 0);
  __syncthreads();

  for (int ti = 0; ti < 8; ++ti){
    int buf = ti & 1;
    if (ti < 7) stage(ti + 1, buf ^ 1);
    short8 kf[4][2], vf[2][4];
#pragma unroll
    for (int kt = 0; kt < 4; ++kt)
#pragma unroll
      for (int ks = 0; ks < 2; ++ks)
        kf[kt][ks] = rdK(buf, kt, ks);
#pragma unroll
    for (int ks = 0; ks < 2; ++ks)
#pragma unroll
      for (int hi = 0; hi < 4; ++hi)
        vf[ks][hi] = rdV(buf, hi, ks);

#pragma unroll
    for (int qi = 0; qi < 4; ++qi){
      f32x4 sa[4];
#pragma unroll
      for (int kt = 0; kt < 4; ++kt){
        sa[kt] = zero4;
#pragma unroll
        for (int ks = 0; ks < 2; ++ks)
          sa[kt] = __builtin_amdgcn_mfma_f32_16x16x32_bf16(kf[kt][ks], qf[qi][ks], sa[kt], 0, 0, 0);
      }
      // scores already in exp2 domain (Q pre-scaled). Row max (qrow = l16).
      float pmax = sa[0][0];
#pragma unroll
      for (int kt = 0; kt < 4; ++kt)
#pragma unroll
        for (int r = 0; r < 4; ++r) pmax = fmaxf(pmax, sa[kt][r]);
      pmax = fmaxf(pmax, __shfl_xor(pmax, 16));
      pmax = fmaxf(pmax, __shfl_xor(pmax, 32));
      // defer-max: rescale only when running max grew by > 8 (P bounded by 2^8)
      if (__any(pmax > m2[qi] + 8.f)){
        float mnew  = fmaxf(m2[qi], pmax);
        float alpha = exp2f(m2[qi] - mnew);
        m2[qi] = mnew;
        lsum[qi] *= alpha;
        float ab[4];
#pragma unroll
        for (int r = 0; r < 4; ++r) ab[r] = __shfl(alpha, g4 * 4 + r);
#pragma unroll
        for (int hi = 0; hi < 4; ++hi)
#pragma unroll
          for (int r = 0; r < 4; ++r) O[qi][hi][r] *= ab[r];
      }
      float m = m2[qi];
      float psum = 0.f;
      u32 w[4][2];
#pragma unroll
      for (int kt = 0; kt < 4; ++kt){
        float p0 = exp2f(sa[kt][0] - m);
        float p1 = exp2f(sa[kt][1] - m);
        float p2 = exp2f(sa[kt][2] - m);
        float p3 = exp2f(sa[kt][3] - m);
        psum += (p0 + p1) + (p2 + p3);
        w[kt][0] = cvtpk(p0, p1);
        w[kt][1] = cvtpk(p2, p3);
      }
      psum += __shfl_xor(psum, 16);
      psum += __shfl_xor(psum, 32);
      lsum[qi] += psum;
      // P -> per-wave LDS (key = kt*16 + g4*4 + {0..3}, qrow = l16)
      u32* prow = (u32*)&Plds[g][l16][0];
#pragma unroll
      for (int kt = 0; kt < 4; ++kt){
        prow[kt * 8 + g4 * 2]     = w[kt][0];
        prow[kt * 8 + g4 * 2 + 1] = w[kt][1];
      }
      short8 pa[2];
#pragma unroll
      for (int ks = 0; ks < 2; ++ks)
        pa[ks] = *(const short8*)&Plds[g][l16][ks * 32 + g4 * 8];
#pragma unroll
      for (int hi = 0; hi < 4; ++hi)
#pragma unroll
        for (int ks = 0; ks < 2; ++ks)
          O[qi][hi] = __builtin_amdgcn_mfma_f32_16x16x32_bf16(pa[ks], vf[ks][hi], O[qi][hi], 0, 0, 0);
    }
    __syncthreads();   // drains this wave's stage loads (vmcnt 0) + retires all buf reads
  }
#pragma unroll
  for (int qi = 0; qi < 4; ++qi){
    float lb[4];
#pragma unroll
    for (int r = 0; r < 4; ++r) lb[r] = 1.0f / __shfl(lsum[qi], g4 * 4 + r);
#pragma unroll
    for (int hi = 0; hi < 4; ++hi)
#pragma unroll
      for (int r = 0; r < 4; ++r){
        int row = rowQ + qi * 16 + g4 * 4 + r;
        int col = qcol + hi * 16 + l16;
        att[(size_t)row * 2048 + col] = f2bf(O[qi][hi][r] * lb[r]);
      }
  }
}

extern "C" void kernel_launch(void* const* d_in, const int* in_sizes, int n_in,
                              void* d_out, int out_size, void* d_ws, size_t ws_size,
                              hipStream_t stream){
  const float* x   = (const float*)d_in[0];
  const float* wq  = (const float*)d_in[1];
  const float* wkv = (const float*)d_in[2];
  const float* wo  = (const float*)d_in[3];
  float* out = (float*)d_out;
  char* ws = (char*)d_ws;

  // workspace layout (67,108,864 B total)
  u16* x_bf  = (u16*)(ws);               // [4096][2048] bf16, 16.78 MB (aliased by att)
  u16* wqkvt = (u16*)(ws + 16777216);    // [3072][2048] bf16, 12.58 MB
  u16* wot   = (u16*)(ws + 29360128);    // [2048][2048] bf16,  8.39 MB
  u16* c1    = (u16*)(ws + 37748736);    // [4096][3072] bf16, 25.17 MB (Q|K|V)
  u16* vt    = (u16*)(ws + 62914560);    // [16*8][64][256] bf16, 4.19 MB
  u16* att   = x_bf;                     // alias: x_bf dead after GEMM1

  // fused preprocessing: cvt (4096) + wq-T (4096) + wkv-T (2048) + wo-T (4096)
  k_prep<<<14336, 256, 0, stream>>>(x, wq, wkv, wo, x_bf, wqkvt, wot);
  // QKV projection (Q cols pre-scaled): BM=128 BN=192, 512 blocks = 2/CU
  k_gemm8p<128, 192, 2, 3, 2, 3, true,  u16  ><<<512, 512, 0, stream>>>(x_bf, wqkvt, c1, 3072, 2048);
  k_vt<<<512, 256, 0, stream>>>(c1, vt);
  k_attn<<<512, 256, 0, stream>>>(c1, vt, att);
  // output projection: BM=128 BN=128, 512 blocks = 2/CU
  k_gemm8p<128, 128, 2, 2, 2, 2, false, float><<<512, 512, 0, stream>>>(att, wot, out, 2048, 2048);
}